// Round 1
// baseline (80.671 us; speedup 1.0000x reference)
//
#include <hip/hip_runtime.h>
#include <math.h>

#define N_STATIONS 276
#define CTX 384          // context_len
#define TGT 96           // target_len
#define BATCH 4096

// One block (256 threads) per sample.
// 16 groups of 16 lanes; each group computes 6 of the 96 output rows.
// Each lane holds 6 float4 (24 floats) of the normalized z row in registers.
__global__ __launch_bounds__(256) void nlinear_kernel(
    const float* __restrict__ z,        // (BATCH, CTX)
    const int*   __restrict__ stations, // (BATCH,)
    const float* __restrict__ W,        // (N_STATIONS, TGT, CTX)
    const float* __restrict__ bias,     // (N_STATIONS, TGT)
    const float* __restrict__ loc,      // (N_STATIONS,)
    const float* __restrict__ scale,    // (N_STATIONS,)
    float*       __restrict__ out)      // (BATCH, TGT)
{
    const int b   = blockIdx.x;
    const int tid = threadIdx.x;
    const int t   = tid & 15;   // lane within 16-lane group
    const int grp = tid >> 4;   // group index 0..15 (block-wide)

    const int   s   = stations[b];
    const float lc  = loc[s];
    const float sc  = scale[s];
    const float inv = 1.0f / sc;

    // Load + normalize z row into registers: lane t owns float4s {t, t+16, ..., t+80}
    const float4* z4 = reinterpret_cast<const float4*>(z + (size_t)b * CTX);
    float4 zn[6];
#pragma unroll
    for (int k = 0; k < 6; ++k) {
        float4 v = z4[t + 16 * k];
        zn[k].x = (v.x - lc) * inv;
        zn[k].y = (v.y - lc) * inv;
        zn[k].z = (v.z - lc) * inv;
        zn[k].w = (v.w - lc) * inv;
    }

    const float* Wbase = W + (size_t)s * TGT * CTX;

#pragma unroll
    for (int it = 0; it < 6; ++it) {
        const int o = grp * 6 + it;   // output row owned by this group this iter
        const float4* w4 = reinterpret_cast<const float4*>(Wbase + (size_t)o * CTX);
        float acc = 0.0f;
#pragma unroll
        for (int k = 0; k < 6; ++k) {
            float4 w = w4[t + 16 * k];
            acc += w.x * zn[k].x + w.y * zn[k].y + w.z * zn[k].z + w.w * zn[k].w;
        }
        // reduce across the 16-lane group (xor offsets stay inside the group)
#pragma unroll
        for (int off = 8; off > 0; off >>= 1)
            acc += __shfl_xor(acc, off, 64);
        if (t == 0) {
            float v = (acc + bias[(size_t)s * TGT + o]) * sc + lc;
            // jax.nn.softplus(x) = max(x,0) + log1p(exp(-|x|))
            out[(size_t)b * TGT + o] = fmaxf(v, 0.0f) + log1pf(expf(-fabsf(v)));
        }
    }
}

extern "C" void kernel_launch(void* const* d_in, const int* in_sizes, int n_in,
                              void* d_out, int out_size, void* d_ws, size_t ws_size,
                              hipStream_t stream) {
    const float* z        = (const float*)d_in[0];
    const int*   stations = (const int*)  d_in[1];
    const float* W        = (const float*)d_in[2];
    const float* bias     = (const float*)d_in[3];
    const float* loc      = (const float*)d_in[4];
    const float* scale    = (const float*)d_in[5];
    float* out = (float*)d_out;

    nlinear_kernel<<<BATCH, 256, 0, stream>>>(z, stations, W, bias, loc, scale, out);
}

// Round 2
// 51.365 us; speedup vs baseline: 1.5705x; 1.5705x over previous
//
#include <hip/hip_runtime.h>
#include <math.h>

#define N_STATIONS 276
#define CTX 384
#define CTX4 96          // float4s per z row
#define TGT 96
#define BATCH 4096
#define SPLIT 2
#define ROWS_PER_BLOCK 48  // TGT / SPLIT
#define R 3                // rows per 16-lane group (16*3 = 48)
#define MAXM 96            // max samples per station (mean 14.8, sigma 3.8 -> 96 is ~21 sigma)
#define MCH 32             // samples staged in LDS per chunk
#define LDS_ROW_F4 97      // 96 + 1 float4 pad -> 2-way (free) bank access

// Grid: 276 stations x 2 row-halves = 552 blocks, 256 threads.
// Each block: scan stations -> sample list; hold its 48 W rows in registers
// (read once); stage normalized z in LDS; loop samples 2 at a time.
__global__ __launch_bounds__(256) void nlinear_grouped(
    const float* __restrict__ z,        // (BATCH, CTX)
    const int*   __restrict__ stations, // (BATCH,)
    const float* __restrict__ W,        // (N_STATIONS, TGT, CTX)
    const float* __restrict__ bias,     // (N_STATIONS, TGT)
    const float* __restrict__ loc,      // (N_STATIONS,)
    const float* __restrict__ scale,    // (N_STATIONS,)
    float*       __restrict__ out)      // (BATCH, TGT)
{
    __shared__ float4 zn[MCH * LDS_ROW_F4];
    __shared__ int list[MAXM];
    __shared__ int mcount;

    const int bid = blockIdx.x;
    const int s   = bid >> 1;   // station
    const int h   = bid & 1;    // row half
    const int tid = threadIdx.x;
    const int t   = tid & 15;   // lane in 16-lane group
    const int grp = tid >> 4;   // group 0..15

    // --- W rows into registers (issued early; independent of the scan) ---
    const int row0 = h * ROWS_PER_BLOCK + grp * R;
    const float4* w4 = reinterpret_cast<const float4*>(W) + ((size_t)s * TGT + row0) * CTX4;
    float4 wr[R][6];
#pragma unroll
    for (int r = 0; r < R; ++r)
#pragma unroll
        for (int k = 0; k < 6; ++k)
            wr[r][k] = w4[(size_t)r * CTX4 + t + 16 * k];

    // --- build sample list for this station ---
    if (tid == 0) mcount = 0;
    __syncthreads();
    for (int b = tid; b < BATCH; b += 256) {
        if (stations[b] == s) {
            int p = atomicAdd(&mcount, 1);
            if (p < MAXM) list[p] = b;
        }
    }
    __syncthreads();
    int m = mcount;
    if (m > MAXM) m = MAXM;
    if (m == 0) return;

    const float lc  = loc[s];
    const float sc  = scale[s];
    const float inv = 1.0f / sc;

    const float4* z4 = reinterpret_cast<const float4*>(z);

    for (int c0 = 0; c0 < m; c0 += MCH) {
        int mch = m - c0; if (mch > MCH) mch = MCH;
        if (c0 > 0) __syncthreads();   // all groups done with previous chunk
        // --- stage normalized z rows into LDS (coalesced) ---
        for (int idx = tid; idx < mch * CTX4; idx += 256) {
            int j = idx / CTX4;
            int q = idx - j * CTX4;
            float4 v = z4[(size_t)list[c0 + j] * CTX4 + q];
            float4 vn;
            vn.x = (v.x - lc) * inv;
            vn.y = (v.y - lc) * inv;
            vn.z = (v.z - lc) * inv;
            vn.w = (v.w - lc) * inv;
            zn[j * LDS_ROW_F4 + q] = vn;
        }
        __syncthreads();

        // --- compute: 2 samples per iteration vs register-resident W ---
        for (int jt = 0; jt < mch; jt += 2) {
            const int  j1   = (jt + 1 < mch) ? jt + 1 : jt;  // clamp; write guarded
            float4 za[6], zb[6];
#pragma unroll
            for (int k = 0; k < 6; ++k) {
                za[k] = zn[jt * LDS_ROW_F4 + t + 16 * k];
                zb[k] = zn[j1 * LDS_ROW_F4 + t + 16 * k];
            }
            float accA[R], accB[R];
#pragma unroll
            for (int r = 0; r < R; ++r) {
                float a0 = 0.f, a1 = 0.f;
#pragma unroll
                for (int k = 0; k < 6; ++k) {
                    a0 += wr[r][k].x * za[k].x + wr[r][k].y * za[k].y
                        + wr[r][k].z * za[k].z + wr[r][k].w * za[k].w;
                    a1 += wr[r][k].x * zb[k].x + wr[r][k].y * zb[k].y
                        + wr[r][k].z * zb[k].z + wr[r][k].w * zb[k].w;
                }
                accA[r] = a0; accB[r] = a1;
            }
            // 16-lane butterfly; all lanes end with the full sums
#pragma unroll
            for (int off = 8; off > 0; off >>= 1) {
#pragma unroll
                for (int r = 0; r < R; ++r) {
                    accA[r] += __shfl_xor(accA[r], off, 64);
                    accB[r] += __shfl_xor(accB[r], off, 64);
                }
            }
            // lane 0 writes sample jt, lane 8 writes sample j1
            const bool wA = (t == 0);
            const bool wB = (t == 8) && (jt + 1 < mch);
            if (wA || wB) {
                const int jj = wB ? j1 : jt;
                const int b  = list[c0 + jj];
                float* op = out + (size_t)b * TGT + row0;
#pragma unroll
                for (int r = 0; r < R; ++r) {
                    float v = wB ? accB[r] : accA[r];
                    v = (v + bias[(size_t)s * TGT + row0 + r]) * sc + lc;
                    op[r] = fmaxf(v, 0.f) + log1pf(expf(-fabsf(v)));
                }
            }
        }
    }
}

extern "C" void kernel_launch(void* const* d_in, const int* in_sizes, int n_in,
                              void* d_out, int out_size, void* d_ws, size_t ws_size,
                              hipStream_t stream) {
    const float* z        = (const float*)d_in[0];
    const int*   stations = (const int*)  d_in[1];
    const float* W        = (const float*)d_in[2];
    const float* bias     = (const float*)d_in[3];
    const float* loc      = (const float*)d_in[4];
    const float* scale    = (const float*)d_in[5];
    float* out = (float*)d_out;

    nlinear_grouped<<<N_STATIONS * SPLIT, 256, 0, stream>>>(
        z, stations, W, bias, loc, scale, out);
}